// Round 15
// baseline (226.466 us; speedup 1.0000x reference)
//
#include <hip/hip_runtime.h>
#include <hip/hip_bf16.h>

// Problem constants: B=4, L=2048, H=8, D=64, SAMPLE_K=N_TOP=40
#define BB 4
#define LL 2048
#define HH 8
#define DD 64
#define SK 40
#define NT 40
#define CH 256              // keys per attn chunk
#define NCH (LL / CH)       // 8 chunks per (b,h)
#define QH 20               // queries per attn block (40 split in 2)

#define WS 10               // samples per wave (4 waves x 10 = 40)
#define HB 68               // padded h-block stride in dwords (64 data + 4 pad)
#define RS (HH * HB)        // 544 dwords per row; bank-conflict-free (round 13: 7.86M -> 0)

// ---------------------------------------------------------------------------
// Kernel 1: M scores. UNCHANGED from round 13/14: three independent
// structures (block-barrier LDS dbuf, async DMA, wave-private pipeline)
// all converge at ~15.8 TB/s logical L2 gather (671 MB / ~43 us) ->
// practical L2 gather-service ceiling for 512-B random-row segments.
// ---------------------------------------------------------------------------
__global__ __launch_bounds__(256) void compute_m_kernel(
        const float* __restrict__ Q, const float* __restrict__ K,
        const int* __restrict__ idx, float* __restrict__ M) {
    __shared__ float kbuf[4][2][2 * RS];   // 34.8 KB
    __shared__ int sidx[SK];
    __shared__ float2 mlpart[4][HH];

    int blk = blockIdx.x;
    int x = blk & 7, g = blk >> 3;
    int b = x >> 1;                    // XCD pair -> batch (K[b] L2-resident)
    int l = (g << 1) | (x & 1);
    int t = threadIdx.x;

    if (t < SK) sidx[t] = idx[(size_t)l * SK + t];

    int lane = t & 63, w = t >> 6;
    int s_lo = lane >> 5;
    int h    = (lane >> 2) & 7;
    int q    = lane & 3;

    const float4* Qb = (const float4*)(Q + ((size_t)b * LL + l) * 512 + h * 64 + q * 16);
    float4 qf0 = Qb[0], qf1 = Qb[1], qf2 = Qb[2], qf3 = Qb[3];

    const float* Kb = K + (size_t)b * LL * 512;

    int r  = lane >> 5;
    int cw = lane & 31;
    int av = cw >> 4;
    int c4 = (4 * cw) & 63;
    __syncthreads();                   // sidx ready

    float4 ra0, ra1, ra2, ra3;
    float4 rb0, rb1, rb2, rb3;

    #define LOADX(p, d0, d1, d2, d3) do {                                       \
        const float* src = Kb + (size_t)sidx[w * WS + (p) * 2 + r] * 512        \
                         + cw * 4;                                              \
        d0 = *(const float4*)(src);                                             \
        d1 = *(const float4*)(src + 128);                                       \
        d2 = *(const float4*)(src + 256);                                       \
        d3 = *(const float4*)(src + 384);                                       \
    } while (0)
    #define WRITEX(slot, d0, d1, d2, d3) do {                                   \
        float* base = &kbuf[w][slot][r * RS + c4];                              \
        *(float4*)(base + (av + 0) * HB) = d0;                                  \
        *(float4*)(base + (av + 2) * HB) = d1;                                  \
        *(float4*)(base + (av + 4) * HB) = d2;                                  \
        *(float4*)(base + (av + 6) * HB) = d3;                                  \
    } while (0)
    #define CONSUME(slot) do {                                                  \
        asm volatile("s_waitcnt lgkmcnt(0)" ::: "memory");                      \
        const float* kb = &kbuf[w][slot][s_lo * RS + h * HB + q * 16];          \
        float4 k0 = *(const float4*)(kb);                                       \
        float4 k1 = *(const float4*)(kb + 4);                                   \
        float4 k2 = *(const float4*)(kb + 8);                                   \
        float4 k3 = *(const float4*)(kb + 12);                                  \
        float pd = qf0.x*k0.x + qf0.y*k0.y + qf0.z*k0.z + qf0.w*k0.w            \
                 + qf1.x*k1.x + qf1.y*k1.y + qf1.z*k1.z + qf1.w*k1.w            \
                 + qf2.x*k2.x + qf2.y*k2.y + qf2.z*k2.z + qf2.w*k2.w            \
                 + qf3.x*k3.x + qf3.y*k3.y + qf3.z*k3.z + qf3.w*k3.w;           \
        pd += __shfl_xor(pd, 1, 64);                                            \
        pd += __shfl_xor(pd, 2, 64);                                            \
        mx = fmaxf(mx, pd);                                                     \
        sm += pd;                                                               \
    } while (0)

    float mx = -INFINITY, sm = 0.0f;

    LOADX(0, ra0, ra1, ra2, ra3);
    LOADX(1, rb0, rb1, rb2, rb3);
    WRITEX(0, ra0, ra1, ra2, ra3);

    LOADX(2, ra0, ra1, ra2, ra3);
    CONSUME(0);
    WRITEX(1, rb0, rb1, rb2, rb3);

    LOADX(3, rb0, rb1, rb2, rb3);
    CONSUME(1);
    WRITEX(0, ra0, ra1, ra2, ra3);

    LOADX(4, ra0, ra1, ra2, ra3);
    CONSUME(0);
    WRITEX(1, rb0, rb1, rb2, rb3);

    CONSUME(1);
    WRITEX(0, ra0, ra1, ra2, ra3);

    CONSUME(0);

    #undef LOADX
    #undef WRITEX
    #undef CONSUME

    mx = fmaxf(mx, __shfl_xor(mx, 32, 64));
    sm += __shfl_xor(sm, 32, 64);

    if ((lane & 0x23) == 0)
        mlpart[w][h] = make_float2(mx, sm);
    __syncthreads();

    if (t < HH) {
        float MX = -INFINITY, SM = 0.0f;
        #pragma unroll
        for (int w2 = 0; w2 < 4; ++w2) {
            float2 ml = mlpart[w2][t];
            MX = fmaxf(MX, ml.x);
            SM += ml.y;
        }
        M[((size_t)b * HH + t) * LL + l] = MX - SM * (1.0f / (float)LL);
    }
}

// ---------------------------------------------------------------------------
// Kernel 2: top-40 per (b,h). WAVE-PRIVATE extraction: each wave holds its
// 512 keys in 8 regs/lane (packed u64: ordered-float<<11 | (2047-i), unique)
// and runs 40 in-register argmax rounds with NO block barriers (owner lane
// unique since keys unique). Then ONE barrier + wave-0 merge of 4x40
// candidates. Replaces round-14's 80 block barriers. Also zeroes the attn
// last-block counters (runs before attn, stream-ordered).
// ---------------------------------------------------------------------------
__global__ __launch_bounds__(256) void topk_kernel(const float* __restrict__ M,
                                                   int* __restrict__ topi,
                                                   int* __restrict__ cnt) {
    __shared__ unsigned long long cand[4 * NT];   // 160 winners, desc order per wave
    int bh = blockIdx.x;
    int t  = threadIdx.x;
    int lane = t & 63, w = t >> 6;

    if (t == 0) cnt[bh] = 0;   // zero attn merge counter for this bh

    // load 8 keys/lane (wave w owns M[bh][512w .. 512w+511])
    const float* Mb = M + (size_t)bh * LL + (w << 9);
    unsigned long long k[8];
    unsigned long long kmax = 0ULL;
    #pragma unroll
    for (int j = 0; j < 8; ++j) {
        int i = (w << 9) + (j << 6) + lane;
        unsigned int bits = __float_as_uint(Mb[(j << 6) + lane]);
        bits = (bits & 0x80000000u) ? ~bits : (bits | 0x80000000u);
        k[j] = ((unsigned long long)bits << 11) | (unsigned int)(LL - 1 - i);
        if (k[j] > kmax) kmax = k[j];
    }

    #pragma unroll 1
    for (int u = 0; u < NT; ++u) {
        unsigned long long m = kmax;
        #pragma unroll
        for (int off = 32; off >= 1; off >>= 1) {
            unsigned long long o = __shfl_xor(m, off, 64);
            if (o > m) m = o;
        }
        if (lane == 0) cand[w * NT + u] = m;
        if (kmax == m) {               // unique owner (keys unique)
            #pragma unroll
            for (int j = 0; j < 8; ++j) if (k[j] == m) k[j] = 0ULL;
            kmax = 0ULL;
            #pragma unroll
            for (int j = 0; j < 8; ++j) if (k[j] > kmax) kmax = k[j];
        }
    }
    __syncthreads();

    if (w == 0) {                      // merge 160 candidates -> global top-40
        unsigned long long a0 = cand[lane];
        unsigned long long a1 = cand[lane + 64];
        unsigned long long a2 = (lane + 128 < 4 * NT) ? cand[lane + 128] : 0ULL;
        #pragma unroll 1
        for (int u = 0; u < NT; ++u) {
            unsigned long long m = a0;
            if (a1 > m) m = a1;
            if (a2 > m) m = a2;
            #pragma unroll
            for (int off = 32; off >= 1; off >>= 1) {
                unsigned long long o = __shfl_xor(m, off, 64);
                if (o > m) m = o;
            }
            if (lane == 0) topi[bh * NT + u] = (LL - 1) - (int)(m & 0x7FF);
            if (a0 == m) a0 = 0ULL;
            if (a1 == m) a1 = 0ULL;
            if (a2 == m) a2 = 0ULL;
        }
    }
}

// ---------------------------------------------------------------------------
// Kernel 3: flash-chunked attention, query-split, WITH FUSED MERGE.
// Partial-chunk math unchanged (round 7 spill fix, round 8 float2 pml).
// Last-block pattern: after writing partials, __threadfence + device-scope
// atomicAdd(cnt[bh]); the 16th block (8 chunks x 2 halves) re-fences and
// computes the final softmax merge for all 40 u of this bh — removes the
// separate merge kernel launch (+gap). Fences per G16 (cross-XCD).
// ---------------------------------------------------------------------------
__global__ __launch_bounds__(256, 3) void attn_kernel(
        const float* __restrict__ Q, const float* __restrict__ K,
        const float* __restrict__ V, const int* __restrict__ topi,
        float2* pml, float* po, int* cnt, float* __restrict__ out) {
    __shared__ float  qs[QH][DD];
    __shared__ float4 e4buf[4][64];
    __shared__ float  oarea[4][QH][DD];
    __shared__ float  mlarea[4][QH][2];
    __shared__ int    amlast;

    int blk = blockIdx.x;
    int qh  = blk >> 8;
    int cc2 = blk & 255;
    int c   = cc2 & (NCH - 1);
    int bh  = cc2 >> 3;
    int h = bh & (HH - 1), b = bh >> 3;
    int t = threadIdx.x, lane = t & 63, w = t >> 6;
    int u0 = qh * QH;

    for (int i = t; i < QH * DD; i += 256) {
        int u = i >> 6, d = i & 63;
        int lq = topi[bh * NT + u0 + u];
        qs[u][d] = Q[(((size_t)b * LL + lq) * HH + h) * DD + d];
    }

    int key = c * CH + w * 64 + lane;
    const float4* kr = (const float4*)&K[(((size_t)b * LL + key) * HH + h) * DD];
    float4 kreg[16];
    #pragma unroll
    for (int j = 0; j < 16; ++j) kreg[j] = kr[j];

    float vcol[64];
    const float* vb = &V[(((size_t)b * LL + c * CH + w * 64) * HH + h) * DD + lane];
    #pragma unroll
    for (int j = 0; j < 64; ++j) vcol[j] = vb[(size_t)j * HH * DD];

    __syncthreads();   // qs ready

    for (int uq = 0; uq < QH / 4; ++uq) {
        float o0 = 0, o1 = 0, o2 = 0, o3 = 0;
        float mv0, mv1, mv2, mv3, lv0, lv1, lv2, lv3;
        float4 ev;
        #pragma unroll
        for (int j = 0; j < 4; ++j) {
            int u = uq * 4 + j;
            const float4* q4 = (const float4*)&qs[u][0];
            float s = 0.0f;
            #pragma unroll
            for (int cc = 0; cc < 16; ++cc) {
                float4 qv = q4[cc];
                s += qv.x * kreg[cc].x + qv.y * kreg[cc].y
                   + qv.z * kreg[cc].z + qv.w * kreg[cc].w;
            }
            s *= 0.125f;   // 1/sqrt(64)
            float m = s;
            #pragma unroll
            for (int off = 32; off >= 1; off >>= 1)
                m = fmaxf(m, __shfl_xor(m, off, 64));
            float e = __expf(s - m);
            float ls = e;
            #pragma unroll
            for (int off = 32; off >= 1; off >>= 1)
                ls += __shfl_xor(ls, off, 64);
            if (j == 0) { mv0 = m; lv0 = ls; ev.x = e; }
            if (j == 1) { mv1 = m; lv1 = ls; ev.y = e; }
            if (j == 2) { mv2 = m; lv2 = ls; ev.z = e; }
            if (j == 3) { mv3 = m; lv3 = ls; ev.w = e; }
        }
        e4buf[w][lane] = ev;
        asm volatile("s_waitcnt lgkmcnt(0)" ::: "memory");
        #pragma unroll
        for (int l2 = 0; l2 < 64; ++l2) {
            float4 e = e4buf[w][l2];
            float  v = vcol[l2];
            o0 += e.x * v; o1 += e.y * v; o2 += e.z * v; o3 += e.w * v;
        }
        oarea[w][uq * 4 + 0][lane] = o0;
        oarea[w][uq * 4 + 1][lane] = o1;
        oarea[w][uq * 4 + 2][lane] = o2;
        oarea[w][uq * 4 + 3][lane] = o3;
        if (lane == 0) {
            mlarea[w][uq * 4 + 0][0] = mv0; mlarea[w][uq * 4 + 0][1] = lv0;
            mlarea[w][uq * 4 + 1][0] = mv1; mlarea[w][uq * 4 + 1][1] = lv1;
            mlarea[w][uq * 4 + 2][0] = mv2; mlarea[w][uq * 4 + 2][1] = lv2;
            mlarea[w][uq * 4 + 3][0] = mv3; mlarea[w][uq * 4 + 3][1] = lv3;
        }
    }
    __syncthreads();

    for (int i = t; i < QH * DD; i += 256) {
        int u = i >> 6, d = i & 63;
        float m0 = mlarea[0][u][0], m1 = mlarea[1][u][0];
        float m2 = mlarea[2][u][0], m3 = mlarea[3][u][0];
        float mb = fmaxf(fmaxf(m0, m1), fmaxf(m2, m3));
        float s0 = __expf(m0 - mb), s1 = __expf(m1 - mb);
        float s2 = __expf(m2 - mb), s3 = __expf(m3 - mb);
        float ob = oarea[0][u][d] * s0 + oarea[1][u][d] * s1
                 + oarea[2][u][d] * s2 + oarea[3][u][d] * s3;
        int gu = u0 + u;
        po[((size_t)(bh * NT + gu) * NCH + c) * DD + d] = ob;
        if (d == 0) {
            float lb = mlarea[0][u][1] * s0 + mlarea[1][u][1] * s1
                     + mlarea[2][u][1] * s2 + mlarea[3][u][1] * s3;
            pml[(bh * NT + gu) * NCH + c] = make_float2(mb, lb);
        }
    }

    // ---- fused merge: last of the 16 blocks for this bh finishes the job ----
    __threadfence();                       // release: partials visible device-wide
    if (t == 0) {
        int old = atomicAdd(&cnt[bh], 1);  // device scope
        amlast = (old == 2 * NCH - 1);
    }
    __syncthreads();
    if (amlast) {
        __threadfence();                   // acquire: see remote partials
        for (int i = t; i < NT * DD; i += 256) {
            int u = i >> 6, d = i & 63;
            int base = (bh * NT + u) * NCH;
            float m = -INFINITY;
            #pragma unroll
            for (int cc = 0; cc < NCH; ++cc) m = fmaxf(m, pml[base + cc].x);
            float lsum = 0.0f, o = 0.0f;
            #pragma unroll
            for (int cc = 0; cc < NCH; ++cc) {
                float2 ml = pml[base + cc];
                float sc = __expf(ml.x - m);
                lsum += ml.y * sc;
                o    += po[(size_t)(base + cc) * DD + d] * sc;
            }
            out[(((size_t)b * NT + u) * HH + h) * DD + d] = o / lsum;
        }
    }
}

extern "C" void kernel_launch(void* const* d_in, const int* in_sizes, int n_in,
                              void* d_out, int out_size, void* d_ws, size_t ws_size,
                              hipStream_t stream) {
    const float* Q   = (const float*)d_in[0];
    const float* K   = (const float*)d_in[1];
    const float* V   = (const float*)d_in[2];
    const int*   idx = (const int*)d_in[3];
    float* out = (float*)d_out;

    char* ws = (char*)d_ws;
    float*  M    = (float*)ws;                        ws += (size_t)BB * HH * LL * sizeof(float);
    int*    topi = (int*)ws;                          ws += (size_t)BB * HH * NT * sizeof(int);
    float2* pml  = (float2*)ws;                       ws += (size_t)BB * HH * NT * NCH * sizeof(float2);
    float*  po   = (float*)ws;                        ws += (size_t)BB * HH * NT * NCH * DD * sizeof(float);
    int*    cnt  = (int*)ws;                          // 32 ints (zeroed in topk)

    hipLaunchKernelGGL(compute_m_kernel, dim3(BB * LL), dim3(256), 0, stream,
                       Q, K, idx, M);
    hipLaunchKernelGGL(topk_kernel, dim3(BB * HH), dim3(256), 0, stream, M, topi, cnt);
    hipLaunchKernelGGL(attn_kernel, dim3(2 * BB * HH * NCH), dim3(256), 0, stream,
                       Q, K, V, topi, pml, po, cnt, out);
}